// Round 8
// baseline (163.760 us; speedup 1.0000x reference)
//
#include <hip/hip_runtime.h>
#include <hip/hip_bf16.h>

typedef __bf16 bf16;
typedef bf16 bf16x4 __attribute__((ext_vector_type(4)));
typedef bf16 bf16x8 __attribute__((ext_vector_type(8)));
typedef float f32x4 __attribute__((ext_vector_type(4)));

#define MFMA32(A, B, C) __builtin_amdgcn_mfma_f32_16x16x32_bf16(A, B, C, 0, 0, 0)
#define GL2LDS16(gp, lp)                                                            \
  __builtin_amdgcn_global_load_lds((const __attribute__((address_space(1))) unsigned int*)(gp), \
                                   (__attribute__((address_space(3))) unsigned int*)(lp), 16, 0, 0)

static constexpr float SCALE = 0.17677669529663687f;  // 1/sqrt(32)
static constexpr float LOG2E = 1.4426950408889634f;

// ---------------- merged prep: convert x, transpose+convert weights, gather bias
// bias layout (S^T C-layout): rbb[h][qt64][kt64][lane64][r4], value =
//   bias[qrow = qt*16 + (lane&15)][key = kt*16 + (lane>>4)*4 + r] * LOG2E
__global__ __launch_bounds__(256) void k_prep(const float* __restrict__ x,
                                              const float* __restrict__ wqkv,
                                              const float* __restrict__ wout,
                                              const float* __restrict__ table,
                                              const int* __restrict__ ridx,
                                              bf16* __restrict__ xb, bf16* __restrict__ wtq,
                                              bf16* __restrict__ wto, bf16* __restrict__ rbb) {
  const int tid = threadIdx.x;
  const int blk = blockIdx.x;
  if (blk < 2048) {
    int t = blk * 256 + tid;
    const float4* s = reinterpret_cast<const float4*>(x) + (size_t)t * 2;
    float4 a = s[0], c = s[1];
    bf16x8 o;
    o[0] = (bf16)a.x; o[1] = (bf16)a.y; o[2] = (bf16)a.z; o[3] = (bf16)a.w;
    o[4] = (bf16)c.x; o[5] = (bf16)c.y; o[6] = (bf16)c.z; o[7] = (bf16)c.w;
    reinterpret_cast<bf16x8*>(xb)[t] = o;
  } else if (blk < 3072) {
    int t = (blk - 2048) * 256 + tid;
    if (t < 196608) {
      int n = t >> 8, k = t & 255;
      wtq[t] = (bf16)wqkv[k * 768 + n];
    } else {
      int t2 = t - 196608;
      int n = t2 >> 8, k = t2 & 255;
      wto[t2] = (bf16)wout[k * 256 + n];
    }
  } else {
    const int bb2 = blk - 3072;  // (qt,kt) tile
    const int qt = bb2 >> 6, kt = bb2 & 63;
    const int r = tid & 3, lane = tid >> 2;
    const int ln = lane & 15, quad = lane >> 4;
    const int qrow = qt * 16 + ln;
    const int key = kt * 16 + quad * 4 + r;
    const int idx = ridx[qrow * 1024 + key];
    const float4* p = reinterpret_cast<const float4*>(table) + idx * 2;
    float4 a = p[0], c = p[1];
    float vals[8] = {a.x, a.y, a.z, a.w, c.x, c.y, c.z, c.w};
    const int base = bb2 * 256 + tid;
#pragma unroll
    for (int h = 0; h < 8; ++h) rbb[h * 1048576 + base] = (bf16)(vals[h] * LOG2E);
  }
}

// ------------------------ 128x128x(BK=32) bf16 MFMA GEMM, m97-style GL2LDS staging
// Double-buffered LDS tiles staged via global_load_lds width-16; ONE barrier per
// K-step; prefetch for step k+1 issues right after barrier k (1-deep pipeline).
// EPI 0 epilogue: q (*scale*log2e) [b,h,n,d]; k [b,h,n,d];
//   v -> vt[b,h,d,kcol] with within-64-key permutation p=(nt,quad,r) -> c=(quad,nt,r)
// EPI 1: out epilogue -> fp32 out[m][256] + b_out
template <int EPI>
__global__ __launch_bounds__(256) void k_gemm(const bf16* __restrict__ A,
                                              const bf16* __restrict__ Bt,
                                              bf16* __restrict__ q, bf16* __restrict__ kk,
                                              bf16* __restrict__ vt, float* __restrict__ out,
                                              const float* __restrict__ bout) {
  __shared__ __align__(16) bf16 As[2][4096];  // [row128][col32] flat
  __shared__ __align__(16) bf16 Bs[2][4096];
  const int tid = threadIdx.x;
  const int ln = tid & 15, quad = (tid >> 4) & 3, wv = tid >> 6;
  const int wm = (wv >> 1) * 64, wn = (wv & 1) * 64;
  const int m0 = blockIdx.x * 128, n0 = blockIdx.y * 128;
  const int srow = tid >> 2, scg = (tid & 3) * 8;  // 4 threads/row, 8 bf16 each
  const bf16* ag = A + (size_t)(m0 + srow) * 256 + scg;
  const bf16* bg = Bt + (size_t)(n0 + srow) * 256 + scg;
  f32x4 acc[4][4] = {};

  // stage K-step 0 into buffer 0
  GL2LDS16(ag, &As[0][tid * 8]);
  GL2LDS16(ag + 64 * 256, &As[0][2048 + tid * 8]);
  GL2LDS16(bg, &Bs[0][tid * 8]);
  GL2LDS16(bg + 64 * 256, &Bs[0][2048 + tid * 8]);

#pragma unroll 2
  for (int kt = 0; kt < 256; kt += 32) {
    const int cur = (kt >> 5) & 1, nxt = cur ^ 1;
    __syncthreads();  // staging for `kt` drained; prior reads of nxt consumed
    if (kt < 224) {
      GL2LDS16(ag + kt + 32, &As[nxt][tid * 8]);
      GL2LDS16(ag + 64 * 256 + kt + 32, &As[nxt][2048 + tid * 8]);
      GL2LDS16(bg + kt + 32, &Bs[nxt][tid * 8]);
      GL2LDS16(bg + 64 * 256 + kt + 32, &Bs[nxt][2048 + tid * 8]);
    }
    bf16x8 af[4], bfr[4];
#pragma unroll
    for (int i = 0; i < 4; ++i)
      af[i] = *reinterpret_cast<const bf16x8*>(&As[cur][(wm + i * 16 + ln) * 32 + quad * 8]);
#pragma unroll
    for (int i = 0; i < 4; ++i)
      bfr[i] = *reinterpret_cast<const bf16x8*>(&Bs[cur][(wn + i * 16 + ln) * 32 + quad * 8]);
#pragma unroll
    for (int i = 0; i < 4; ++i)
#pragma unroll
      for (int j = 0; j < 4; ++j) acc[i][j] = MFMA32(af[i], bfr[j], acc[i][j]);
  }

  if (EPI == 0) {
    const int colbase = n0 + wn;
    const int seg = colbase >> 8;
    const int cb = colbase & 255;
    const float mul = (seg == 0) ? SCALE * LOG2E : 1.0f;
#pragma unroll
    for (int i = 0; i < 4; ++i) {
      const int gm = m0 + wm + i * 16 + quad * 4;
      const int b = gm >> 10;
#pragma unroll
      for (int j = 0; j < 4; ++j) {
        const int gc = cb + j * 16 + ln;
        const int h = gc >> 5, d = gc & 31;
#pragma unroll
        for (int r = 0; r < 4; ++r) {
          const int nseq = (gm + r) & 1023;
          if (seg == 2) {
            const int p6 = nseq & 63;
            const int c6 = ((p6 >> 2) & 3) * 16 + (p6 >> 4) * 4 + (p6 & 3);
            const int kcol = (nseq & ~63) | c6;
            vt[(b * 8 + h) * 32768 + d * 1024 + kcol] = (bf16)acc[i][j][r];
          } else {
            bf16* dst = (seg == 0) ? q : kk;
            dst[(b * 8 + h) * 32768 + nseq * 32 + d] = (bf16)(acc[i][j][r] * mul);
          }
        }
      }
    }
  } else {
#pragma unroll
    for (int j = 0; j < 4; ++j) {
      const int gc = n0 + wn + j * 16 + ln;
      const float bb = bout[gc];
#pragma unroll
      for (int i = 0; i < 4; ++i) {
        const int gm = m0 + wm + i * 16 + quad * 4;
#pragma unroll
        for (int r = 0; r < 4; ++r) out[(size_t)(gm + r) * 256 + gc] = acc[i][j][r] + bb;
      }
    }
  }
}

// ----------------------------------------------------------------- flash attention
// r7 chassis (GL2LDS-staged K/V, double-buffered, one barrier/iter) with TWO
// q-tiles per wave: grid 1024 = 128 bh x 8 qgroups -> exactly 4 blocks/CU
// (LDS 34.8KB), single tail-free generation (r7's 33% time-avg occupancy was a
// ragged 2nd generation). K-frag LDS reads + K/V staging amortized over 2 tiles.
__global__ __launch_bounds__(256) void k_flash(const bf16* __restrict__ qs,
                                               const bf16* __restrict__ ks,
                                               const bf16* __restrict__ vtg,
                                               const bf16* __restrict__ rbb,
                                               bf16* __restrict__ ao) {
  __shared__ __align__(16) bf16 Ks[2][2048];       // [buf][dseg4][row64][8]
  __shared__ __align__(16) bf16 Vs[2][2048];       // [buf][cg8][d32][8]
  __shared__ __align__(16) bf16 Ps[4][2][16][72];  // [wave][tile][row][col]
  const int tid = threadIdx.x;
  const int lane = tid & 63;
  const int ln = lane & 15, quad = lane >> 4, wv = tid >> 6;
  const int blk = blockIdx.x;
  const int bh = blk & 127;  // %8 == h -> XCD affinity
  const int b = bh >> 3, h = bh & 7;
  const int tA = (blk >> 7) * 8 + wv * 2;  // q-tile pair [0,64)
  const int tB = tA + 1;
  const bf16* qb = qs + bh * 32768;
  const bf16* kb = ks + bh * 32768;
  const bf16* vb = vtg + bh * 32768;
  const bf16* bbA = rbb + h * 1048576 + tA * 16384 + lane * 4;
  const bf16* bbB = rbb + h * 1048576 + tB * 16384 + lane * 4;

  const bf16* kg = kb + lane * 32 + wv * 8;
  const bf16* vg = vb + (lane & 31) * 1024 + (wv * 2 + (lane >> 5)) * 8;

  const bf16x8 qfA = *reinterpret_cast<const bf16x8*>(&qb[(tA * 16 + ln) * 32 + quad * 8]);
  const bf16x8 qfB = *reinterpret_cast<const bf16x8*>(&qb[(tB * 16 + ln) * 32 + quad * 8]);

  f32x4 accA0 = {0.f, 0.f, 0.f, 0.f}, accA1 = {0.f, 0.f, 0.f, 0.f};
  f32x4 accB0 = {0.f, 0.f, 0.f, 0.f}, accB1 = {0.f, 0.f, 0.f, 0.f};
  float lsA = 0.f, lsB = 0.f;

  bf16x4 cbA[2][4], cbB[2][4];
#pragma unroll
  for (int nt = 0; nt < 4; ++nt) {
    cbA[0][nt] = *reinterpret_cast<const bf16x4*>(&bbA[nt * 256]);
    cbB[0][nt] = *reinterpret_cast<const bf16x4*>(&bbB[nt * 256]);
  }
  GL2LDS16(kg, &Ks[0][wv * 512]);
  GL2LDS16(vg, &Vs[0][wv * 512]);

#pragma unroll 2
  for (int it = 0; it < 16; ++it) {
    const int cur = it & 1, nxt = cur ^ 1;
    const int k0 = it * 64;
    __syncthreads();  // tile `it` staged; prior iteration's LDS reads consumed
    const int kpf = (it < 15) ? k0 + 64 : k0;
    GL2LDS16(kg + kpf * 32, &Ks[nxt][wv * 512]);
    GL2LDS16(vg + kpf, &Vs[nxt][wv * 512]);
    const int bnx = (it < 15 ? it + 1 : it) * 4;
#pragma unroll
    for (int nt = 0; nt < 4; ++nt) {
      cbA[nxt][nt] = *reinterpret_cast<const bf16x4*>(&bbA[(bnx + nt) * 256]);
      cbB[nxt][nt] = *reinterpret_cast<const bf16x4*>(&bbB[(bnx + nt) * 256]);
    }
    // K frags (shared by both q-tiles)
    bf16x8 kf[4];
#pragma unroll
    for (int nt = 0; nt < 4; ++nt)
      kf[nt] = *reinterpret_cast<const bf16x8*>(&Ks[cur][quad * 512 + (nt * 16 + ln) * 8]);
    // S^T = K*Q^T with bias C-init (exp2 domain)
    f32x4 sA[4], sB[4];
#pragma unroll
    for (int nt = 0; nt < 4; ++nt) {
      f32x4 cA, cB;
#pragma unroll
      for (int e = 0; e < 4; ++e) {
        cA[e] = (float)cbA[cur][nt][e];
        cB[e] = (float)cbB[cur][nt][e];
      }
      sA[nt] = MFMA32(kf[nt], qfA, cA);
      sB[nt] = MFMA32(kf[nt], qfB, cB);
    }
    // V frags (permuted layout; shared by both q-tiles)
    bf16x8 va0 = *reinterpret_cast<const bf16x8*>(&Vs[cur][quad * 256 + ln * 8]);
    bf16x8 vc0 = *reinterpret_cast<const bf16x8*>(&Vs[cur][quad * 256 + (16 + ln) * 8]);
    bf16x8 va1 = *reinterpret_cast<const bf16x8*>(&Vs[cur][(4 + quad) * 256 + ln * 8]);
    bf16x8 vc1 = *reinterpret_cast<const bf16x8*>(&Vs[cur][(4 + quad) * 256 + (16 + ln) * 8]);
    // ---- tile A: P = exp2(S); pack c-order; LDS round trip; PV
#pragma unroll
    for (int nt = 0; nt < 4; ++nt)
#pragma unroll
      for (int e = 0; e < 4; ++e) sA[nt][e] = __builtin_amdgcn_exp2f(sA[nt][e]);
#pragma unroll
    for (int nt = 0; nt < 4; ++nt) lsA += (sA[nt][0] + sA[nt][1]) + (sA[nt][2] + sA[nt][3]);
    {
      bf16x8 lo, hi;
#pragma unroll
      for (int e = 0; e < 4; ++e) {
        lo[e] = (bf16)sA[0][e];
        lo[4 + e] = (bf16)sA[1][e];
        hi[e] = (bf16)sA[2][e];
        hi[4 + e] = (bf16)sA[3][e];
      }
      *reinterpret_cast<bf16x8*>(&Ps[wv][0][ln][quad * 16]) = lo;
      *reinterpret_cast<bf16x8*>(&Ps[wv][0][ln][quad * 16 + 8]) = hi;
    }
    // ---- tile B exp2/pack (fills tile A's DS latency)
#pragma unroll
    for (int nt = 0; nt < 4; ++nt)
#pragma unroll
      for (int e = 0; e < 4; ++e) sB[nt][e] = __builtin_amdgcn_exp2f(sB[nt][e]);
#pragma unroll
    for (int nt = 0; nt < 4; ++nt) lsB += (sB[nt][0] + sB[nt][1]) + (sB[nt][2] + sB[nt][3]);
    {
      bf16x8 lo, hi;
#pragma unroll
      for (int e = 0; e < 4; ++e) {
        lo[e] = (bf16)sB[0][e];
        lo[4 + e] = (bf16)sB[1][e];
        hi[e] = (bf16)sB[2][e];
        hi[4 + e] = (bf16)sB[3][e];
      }
      *reinterpret_cast<bf16x8*>(&Ps[wv][1][ln][quad * 16]) = lo;
      *reinterpret_cast<bf16x8*>(&Ps[wv][1][ln][quad * 16 + 8]) = hi;
    }
    // ---- PV for both tiles
    {
      bf16x8 pa0 = *reinterpret_cast<const bf16x8*>(&Ps[wv][0][ln][quad * 8]);
      bf16x8 pa1 = *reinterpret_cast<const bf16x8*>(&Ps[wv][0][ln][32 + quad * 8]);
      accA0 = MFMA32(pa0, va0, accA0);
      accA1 = MFMA32(pa0, vc0, accA1);
      accA0 = MFMA32(pa1, va1, accA0);
      accA1 = MFMA32(pa1, vc1, accA1);
      bf16x8 pb0 = *reinterpret_cast<const bf16x8*>(&Ps[wv][1][ln][quad * 8]);
      bf16x8 pb1 = *reinterpret_cast<const bf16x8*>(&Ps[wv][1][ln][32 + quad * 8]);
      accB0 = MFMA32(pb0, va0, accB0);
      accB1 = MFMA32(pb0, vc0, accB1);
      accB0 = MFMA32(pb1, va1, accB0);
      accB1 = MFMA32(pb1, vc1, accB1);
    }
  }

  // row sums: combine the 4 quads' key partials
  lsA += __shfl_xor(lsA, 16, 64);
  lsA += __shfl_xor(lsA, 32, 64);
  lsB += __shfl_xor(lsB, 16, 64);
  lsB += __shfl_xor(lsB, 32, 64);

#pragma unroll
  for (int r = 0; r < 4; ++r) {
    const float invA = __builtin_amdgcn_rcpf(__shfl(lsA, quad * 4 + r, 64));
    const int rowA = tA * 16 + quad * 4 + r;
    bf16* poA = &ao[(size_t)(b * 1024 + rowA) * 256 + h * 32 + ln];
    poA[0] = (bf16)(accA0[r] * invA);
    poA[16] = (bf16)(accA1[r] * invA);
    const float invB = __builtin_amdgcn_rcpf(__shfl(lsB, quad * 4 + r, 64));
    const int rowB = tB * 16 + quad * 4 + r;
    bf16* poB = &ao[(size_t)(b * 1024 + rowB) * 256 + h * 32 + ln];
    poB[0] = (bf16)(accB0[r] * invB);
    poB[16] = (bf16)(accB1[r] * invB);
  }
}

// ---------------------------------------------------------------------- launcher
extern "C" void kernel_launch(void* const* d_in, const int* in_sizes, int n_in,
                              void* d_out, int out_size, void* d_ws, size_t ws_size,
                              hipStream_t stream) {
  const float* x = (const float*)d_in[0];
  const float* wqkv = (const float*)d_in[1];
  const float* wout = (const float*)d_in[2];
  const float* bout = (const float*)d_in[3];
  const float* btab = (const float*)d_in[4];
  const int* ridx = (const int*)d_in[5];
  float* out = (float*)d_out;

  char* ws = (char*)d_ws;
  bf16* xb  = (bf16*)(ws + 0);           // 8 MB   [16384][256]
  bf16* wtq = (bf16*)(ws + 8388608);     // 384 KB
  bf16* wto = (bf16*)(ws + 8781824);     // 128 KB
  bf16* q   = (bf16*)(ws + 8912896);     // 8 MB   [b,h,n,d] (pre-scaled scale*log2e)
  bf16* k   = (bf16*)(ws + 17301504);    // 8 MB   [b,h,n,d]
  bf16* vt  = (bf16*)(ws + 25690112);    // 8 MB   [b,h,d,n] key-permuted within 64
  bf16* rb  = (bf16*)(ws + 34078720);    // 16 MB  S^T C-layout bias tiles (*log2e)
  bf16* ao  = (bf16*)(ws + 50855936);    // 8 MB   [16384][256]

  k_prep<<<7168, 256, 0, stream>>>(x, wqkv, wout, btab, ridx, xb, wtq, wto, rb);
  k_gemm<0><<<dim3(128, 6), 256, 0, stream>>>(xb, wtq, q, k, vt, nullptr, nullptr);
  k_flash<<<1024, 256, 0, stream>>>(q, k, vt, rb, ao);
  k_gemm<1><<<dim3(128, 2), 256, 0, stream>>>(ao, wto, nullptr, nullptr, nullptr, out, bout);
}

// Round 10
// 155.371 us; speedup vs baseline: 1.0540x; 1.0540x over previous
//
#include <hip/hip_runtime.h>
#include <hip/hip_bf16.h>

typedef __bf16 bf16;
typedef bf16 bf16x4 __attribute__((ext_vector_type(4)));
typedef bf16 bf16x8 __attribute__((ext_vector_type(8)));
typedef short s16x4 __attribute__((ext_vector_type(4)));
typedef float f32x4 __attribute__((ext_vector_type(4)));

#define MFMA32(A, B, C) __builtin_amdgcn_mfma_f32_16x16x32_bf16(A, B, C, 0, 0, 0)
#define MFMA16(A, B, C) __builtin_amdgcn_mfma_f32_16x16x16bf16_1k(A, B, C, 0, 0, 0)
#define GL2LDS16(gp, lp)                                                            \
  __builtin_amdgcn_global_load_lds((const __attribute__((address_space(1))) unsigned int*)(gp), \
                                   (__attribute__((address_space(3))) unsigned int*)(lp), 16, 0, 0)

static constexpr float SCALE = 0.17677669529663687f;  // 1/sqrt(32)
static constexpr float LOG2E = 1.4426950408889634f;

// ---------------- merged prep: convert x, transpose+convert weights, gather bias
// bias layout (S^T C-layout): rbb[h][qt64][kt64][lane64][r4], value =
//   bias[qrow = qt*16 + (lane&15)][key = kt*16 + (lane>>4)*4 + r] * LOG2E
__global__ __launch_bounds__(256) void k_prep(const float* __restrict__ x,
                                              const float* __restrict__ wqkv,
                                              const float* __restrict__ wout,
                                              const float* __restrict__ table,
                                              const int* __restrict__ ridx,
                                              bf16* __restrict__ xb, bf16* __restrict__ wtq,
                                              bf16* __restrict__ wto, bf16* __restrict__ rbb) {
  const int tid = threadIdx.x;
  const int blk = blockIdx.x;
  if (blk < 2048) {
    int t = blk * 256 + tid;
    const float4* s = reinterpret_cast<const float4*>(x) + (size_t)t * 2;
    float4 a = s[0], c = s[1];
    bf16x8 o;
    o[0] = (bf16)a.x; o[1] = (bf16)a.y; o[2] = (bf16)a.z; o[3] = (bf16)a.w;
    o[4] = (bf16)c.x; o[5] = (bf16)c.y; o[6] = (bf16)c.z; o[7] = (bf16)c.w;
    reinterpret_cast<bf16x8*>(xb)[t] = o;
  } else if (blk < 3072) {
    int t = (blk - 2048) * 256 + tid;
    if (t < 196608) {
      int n = t >> 8, k = t & 255;
      wtq[t] = (bf16)wqkv[k * 768 + n];
    } else {
      int t2 = t - 196608;
      int n = t2 >> 8, k = t2 & 255;
      wto[t2] = (bf16)wout[k * 256 + n];
    }
  } else {
    const int bb2 = blk - 3072;  // (qt,kt) tile
    const int qt = bb2 >> 6, kt = bb2 & 63;
    const int r = tid & 3, lane = tid >> 2;
    const int ln = lane & 15, quad = lane >> 4;
    const int qrow = qt * 16 + ln;
    const int key = kt * 16 + quad * 4 + r;
    const int idx = ridx[qrow * 1024 + key];
    const float4* p = reinterpret_cast<const float4*>(table) + idx * 2;
    float4 a = p[0], c = p[1];
    float vals[8] = {a.x, a.y, a.z, a.w, c.x, c.y, c.z, c.w};
    const int base = bb2 * 256 + tid;
#pragma unroll
    for (int h = 0; h < 8; ++h) rbb[h * 1048576 + base] = (bf16)(vals[h] * LOG2E);
  }
}

// ------------------------ 128x128x(BK=32) bf16 MFMA GEMM, m97-style GL2LDS staging
// EPI 0 epilogue: q (*scale*log2e) [b,h,n,d]; k [b,h,n,d]; v -> vt[b,h,d,n] (plain)
// EPI 1: out epilogue -> fp32 out[m][256] + b_out
// NOTE: all GL2LDS prefetches are guarded (kt < 224) so none is outstanding at
// kernel exit — dangling LDS-DMA corrupts the successor block's LDS (r9 bug).
template <int EPI>
__global__ __launch_bounds__(256) void k_gemm(const bf16* __restrict__ A,
                                              const bf16* __restrict__ Bt,
                                              bf16* __restrict__ q, bf16* __restrict__ kk,
                                              bf16* __restrict__ vt, float* __restrict__ out,
                                              const float* __restrict__ bout) {
  __shared__ __align__(16) bf16 As[2][4096];  // [row128][col32] flat
  __shared__ __align__(16) bf16 Bs[2][4096];
  const int tid = threadIdx.x;
  const int ln = tid & 15, quad = (tid >> 4) & 3, wv = tid >> 6;
  const int wm = (wv >> 1) * 64, wn = (wv & 1) * 64;
  const int m0 = blockIdx.x * 128, n0 = blockIdx.y * 128;
  const int srow = tid >> 2, scg = (tid & 3) * 8;
  const bf16* ag = A + (size_t)(m0 + srow) * 256 + scg;
  const bf16* bg = Bt + (size_t)(n0 + srow) * 256 + scg;
  f32x4 acc[4][4] = {};

  GL2LDS16(ag, &As[0][tid * 8]);
  GL2LDS16(ag + 64 * 256, &As[0][2048 + tid * 8]);
  GL2LDS16(bg, &Bs[0][tid * 8]);
  GL2LDS16(bg + 64 * 256, &Bs[0][2048 + tid * 8]);

#pragma unroll 2
  for (int kt = 0; kt < 256; kt += 32) {
    const int cur = (kt >> 5) & 1, nxt = cur ^ 1;
    __syncthreads();
    if (kt < 224) {
      GL2LDS16(ag + kt + 32, &As[nxt][tid * 8]);
      GL2LDS16(ag + 64 * 256 + kt + 32, &As[nxt][2048 + tid * 8]);
      GL2LDS16(bg + kt + 32, &Bs[nxt][tid * 8]);
      GL2LDS16(bg + 64 * 256 + kt + 32, &Bs[nxt][2048 + tid * 8]);
    }
    bf16x8 af[4], bfr[4];
#pragma unroll
    for (int i = 0; i < 4; ++i)
      af[i] = *reinterpret_cast<const bf16x8*>(&As[cur][(wm + i * 16 + ln) * 32 + quad * 8]);
#pragma unroll
    for (int i = 0; i < 4; ++i)
      bfr[i] = *reinterpret_cast<const bf16x8*>(&Bs[cur][(wn + i * 16 + ln) * 32 + quad * 8]);
#pragma unroll
    for (int i = 0; i < 4; ++i)
#pragma unroll
      for (int j = 0; j < 4; ++j) acc[i][j] = MFMA32(af[i], bfr[j], acc[i][j]);
  }

  if (EPI == 0) {
    const int colbase = n0 + wn;
    const int seg = colbase >> 8;
    const int cb = colbase & 255;
    const float mul = (seg == 0) ? SCALE * LOG2E : 1.0f;
#pragma unroll
    for (int i = 0; i < 4; ++i) {
      const int gm = m0 + wm + i * 16 + quad * 4;
      const int b = gm >> 10;
#pragma unroll
      for (int j = 0; j < 4; ++j) {
        const int gc = cb + j * 16 + ln;
        const int h = gc >> 5, d = gc & 31;
#pragma unroll
        for (int r = 0; r < 4; ++r) {
          const int nseq = (gm + r) & 1023;
          if (seg == 2) {
            vt[(b * 8 + h) * 32768 + d * 1024 + nseq] = (bf16)acc[i][j][r];
          } else {
            bf16* dst = (seg == 0) ? q : kk;
            dst[(b * 8 + h) * 32768 + nseq * 32 + d] = (bf16)(acc[i][j][r] * mul);
          }
        }
      }
    }
  } else {
#pragma unroll
    for (int j = 0; j < 4; ++j) {
      const int gc = n0 + wn + j * 16 + ln;
      const float bb = bout[gc];
#pragma unroll
      for (int i = 0; i < 4; ++i) {
        const int gm = m0 + wm + i * 16 + quad * 4;
#pragma unroll
        for (int r = 0; r < 4; ++r) out[(size_t)(gm + r) * 256 + gc] = acc[i][j][r] + bb;
      }
    }
  }
}

// ----------------------------------------------------------------- flash attention
// r9 structure (GL2LDS-staged K/V dbuf + register-direct PV) with the race fixed:
// the r9 last-iteration clamped re-stage was a DANGLING LDS-DMA — issued with no
// consumer and no barrier before s_endpgm, it could land in the successor
// block's LDS (timing-dependent replay corruption). Fix: prefetch only for
// it < 15, plus one trailing __syncthreads() (drains vmcnt across all waves
// before any wave exits).
__global__ __launch_bounds__(256, 6) void k_flash(const bf16* __restrict__ qs,
                                                  const bf16* __restrict__ ks,
                                                  const bf16* __restrict__ vtg,
                                                  const bf16* __restrict__ rbb,
                                                  bf16* __restrict__ ao) {
  __shared__ __align__(16) bf16 Ks[2][2048];  // [buf][row64][d32] natural
  __shared__ __align__(16) bf16 Vs[2][2048];  // [buf][oct8][d32][8]
  const int tid = threadIdx.x;
  const int lane = tid & 63;
  const int ln = lane & 15, quad = lane >> 4, wv = tid >> 6;
  const int blk = blockIdx.x;
  const int bh = blk & 127;  // %8 == h -> XCD affinity
  const int b = bh >> 3, h = bh & 7;
  const int qtw = (blk >> 7) * 4 + wv;  // 16-row q-tile index [0,64)
  const int q0 = qtw * 16;
  const bf16* qb = qs + bh * 32768;
  const bf16* kb = ks + bh * 32768;
  const bf16* vb = vtg + bh * 32768;
  const bf16* bbias = rbb + h * 1048576 + qtw * 16384 + lane * 4;  // + kt16*256

  const bf16* kg = kb + tid * 8;                             // + k0*32 (tile contiguous)
  const bf16* vg = vb + (tid & 31) * 1024 + (tid >> 5) * 8;  // + k0

  // Q as B-operand of MFMA32: B[k=d=quad*8+j][n=qrow=ln]
  const bf16x8 qfrag = *reinterpret_cast<const bf16x8*>(&qb[(q0 + ln) * 32 + quad * 8]);

  f32x4 acc0 = {0.f, 0.f, 0.f, 0.f}, acc1 = {0.f, 0.f, 0.f, 0.f};
  float lsum = 0.f;

  bf16x4 cbf[2][4];
#pragma unroll
  for (int nt = 0; nt < 4; ++nt) cbf[0][nt] = *reinterpret_cast<const bf16x4*>(&bbias[nt * 256]);
  GL2LDS16(kg, &Ks[0][tid * 8]);
  GL2LDS16(vg, &Vs[0][tid * 8]);

#pragma unroll 2
  for (int it = 0; it < 16; ++it) {
    const int cur = it & 1, nxt = cur ^ 1;
    const int k0 = it * 64;
    __syncthreads();  // tile `it` staged; prior iteration's LDS reads consumed
    if (it < 15) {    // guarded: NO dangling LDS-DMA at kernel exit
      GL2LDS16(kg + (k0 + 64) * 32, &Ks[nxt][tid * 8]);
      GL2LDS16(vg + k0 + 64, &Vs[nxt][tid * 8]);
#pragma unroll
      for (int nt = 0; nt < 4; ++nt)
        cbf[nxt][nt] = *reinterpret_cast<const bf16x4*>(&bbias[((it + 1) * 4 + nt) * 256]);
    }
    // K frags: K[k0+nt*16+ln][quad*8..+7]
    bf16x8 kf[4];
#pragma unroll
    for (int nt = 0; nt < 4; ++nt)
      kf[nt] = *reinterpret_cast<const bf16x8*>(&Ks[cur][(nt * 16 + ln) * 32 + quad * 8]);
    // V B-frags for MFMA16: B[k=key=quad*4+j][n=d]; Vs[oct][d][8]
    s16x4 vfa[4], vfc[4];
#pragma unroll
    for (int nt = 0; nt < 4; ++nt) {
      const int base = (2 * nt + (quad >> 1)) * 256 + ln * 8 + (quad & 1) * 4;
      vfa[nt] = *reinterpret_cast<const s16x4*>(&Vs[cur][base]);
      vfc[nt] = *reinterpret_cast<const s16x4*>(&Vs[cur][base + 128]);
    }
    // S^T = K*Q^T with bias C-init (exp2 domain; scale*log2e folded into q)
    f32x4 s[4];
#pragma unroll
    for (int nt = 0; nt < 4; ++nt) {
      f32x4 c;
#pragma unroll
      for (int e = 0; e < 4; ++e) c[e] = (float)cbf[cur][nt][e];
      s[nt] = MFMA32(kf[nt], qfrag, c);
    }
    // P = exp2(S); row sums; pack to MFMA16 A-frags (register identity, r==j)
    s16x4 p[4];
#pragma unroll
    for (int nt = 0; nt < 4; ++nt) {
      bf16x4 t;
#pragma unroll
      for (int e = 0; e < 4; ++e) {
        s[nt][e] = __builtin_amdgcn_exp2f(s[nt][e]);
        t[e] = (bf16)s[nt][e];
      }
      lsum += (s[nt][0] + s[nt][1]) + (s[nt][2] + s[nt][3]);
      p[nt] = __builtin_bit_cast(s16x4, t);
    }
    acc0 = MFMA16(p[0], vfa[0], acc0);
    acc1 = MFMA16(p[0], vfc[0], acc1);
    acc0 = MFMA16(p[1], vfa[1], acc0);
    acc1 = MFMA16(p[1], vfc[1], acc1);
    acc0 = MFMA16(p[2], vfa[2], acc0);
    acc1 = MFMA16(p[2], vfc[2], acc1);
    acc0 = MFMA16(p[3], vfa[3], acc0);
    acc1 = MFMA16(p[3], vfc[3], acc1);
  }
  __syncthreads();  // insurance: drain all waves' outstanding DMA before any exit

  // full row sum for qrow=ln: combine the 4 quads' key partials
  lsum += __shfl_xor(lsum, 16, 64);
  lsum += __shfl_xor(lsum, 32, 64);

  // O C-layout: lane holds O[row=quad*4+r][d=ln (acc0) / 16+ln (acc1)]
#pragma unroll
  for (int r = 0; r < 4; ++r) {
    const float inv = __builtin_amdgcn_rcpf(__shfl(lsum, quad * 4 + r, 64));
    const int row = q0 + quad * 4 + r;
    bf16* po = &ao[(size_t)(b * 1024 + row) * 256 + h * 32 + ln];
    po[0] = (bf16)(acc0[r] * inv);
    po[16] = (bf16)(acc1[r] * inv);
  }
}

// ---------------------------------------------------------------------- launcher
extern "C" void kernel_launch(void* const* d_in, const int* in_sizes, int n_in,
                              void* d_out, int out_size, void* d_ws, size_t ws_size,
                              hipStream_t stream) {
  const float* x = (const float*)d_in[0];
  const float* wqkv = (const float*)d_in[1];
  const float* wout = (const float*)d_in[2];
  const float* bout = (const float*)d_in[3];
  const float* btab = (const float*)d_in[4];
  const int* ridx = (const int*)d_in[5];
  float* out = (float*)d_out;

  char* ws = (char*)d_ws;
  bf16* xb  = (bf16*)(ws + 0);           // 8 MB   [16384][256]
  bf16* wtq = (bf16*)(ws + 8388608);     // 384 KB
  bf16* wto = (bf16*)(ws + 8781824);     // 128 KB
  bf16* q   = (bf16*)(ws + 8912896);     // 8 MB   [b,h,n,d] (pre-scaled scale*log2e)
  bf16* k   = (bf16*)(ws + 17301504);    // 8 MB   [b,h,n,d]
  bf16* vt  = (bf16*)(ws + 25690112);    // 8 MB   [b,h,d,n]
  bf16* rb  = (bf16*)(ws + 34078720);    // 16 MB  S^T C-layout bias tiles (*log2e)
  bf16* ao  = (bf16*)(ws + 50855936);    // 8 MB   [16384][256]

  k_prep<<<7168, 256, 0, stream>>>(x, wqkv, wout, btab, ridx, xb, wtq, wto, rb);
  k_gemm<0><<<dim3(128, 6), 256, 0, stream>>>(xb, wtq, q, k, vt, nullptr, nullptr);
  k_flash<<<2048, 256, 0, stream>>>(q, k, vt, rb, ao);
  k_gemm<1><<<dim3(128, 2), 256, 0, stream>>>(ao, wto, nullptr, nullptr, nullptr, out, bout);
}